// Round 1
// baseline (193.889 us; speedup 1.0000x reference)
//
#include <hip/hip_runtime.h>

// Chamfer distance, B=16, N=M=4096, fp32 3-D points.
// Fused both-directions kernel: grid = 2 dirs x 16 batches x 16 chunks.
// Each block stages the full target cloud (4096 pts) in LDS as float4 (64 KB),
// each thread owns one query point and scans all targets (broadcast LDS reads).

constexpr int BATCH  = 16;
constexpr int NPTS   = 4096;
constexpr int BLOCK  = 256;                 // threads per block (4 waves)
constexpr int CHUNKS = NPTS / BLOCK;        // 16 query-chunks per batch per dir

__global__ void zero_out(float* out) { out[0] = 0.0f; }

__global__ void __launch_bounds__(BLOCK)
chamfer_kernel(const float* __restrict__ x, const float* __restrict__ y,
               float* __restrict__ out) {
    __shared__ float4 q_s[NPTS];            // 64 KB: target cloud, w unused

    const int bid   = blockIdx.x;
    const int dir   = bid & 1;              // 0: x->y, 1: y->x
    const int rest  = bid >> 1;
    const int batch = rest >> 4;            // / CHUNKS (16)
    const int chunk = rest & (CHUNKS - 1);

    const float* __restrict__ P = dir ? y : x;   // query cloud
    const float* __restrict__ Q = dir ? x : y;   // target cloud
    const float* Pb = P + (size_t)batch * NPTS * 3;
    const float* Qb = Q + (size_t)batch * NPTS * 3;

    // Cooperative stage of target cloud into LDS (coalesced-ish: each thread
    // reads 3 consecutive floats; a wave covers 768 contiguous bytes).
    for (int i = threadIdx.x; i < NPTS; i += BLOCK) {
        q_s[i] = make_float4(Qb[3 * i], Qb[3 * i + 1], Qb[3 * i + 2], 0.0f);
    }
    __syncthreads();

    const int   pi = chunk * BLOCK + threadIdx.x;
    const float px = Pb[3 * pi], py = Pb[3 * pi + 1], pz = Pb[3 * pi + 2];

    // 4 independent min chains to break the serial v_min_f32 dependency.
    float b0 = 1e30f, b1 = 1e30f, b2 = 1e30f, b3 = 1e30f;
    for (int j = 0; j < NPTS; j += 4) {
        float4 q0 = q_s[j + 0];
        float4 q1 = q_s[j + 1];
        float4 q2 = q_s[j + 2];
        float4 q3 = q_s[j + 3];
        {
            float dx = px - q0.x, dy = py - q0.y, dz = pz - q0.z;
            b0 = fminf(b0, dx * dx + dy * dy + dz * dz);
        }
        {
            float dx = px - q1.x, dy = py - q1.y, dz = pz - q1.z;
            b1 = fminf(b1, dx * dx + dy * dy + dz * dz);
        }
        {
            float dx = px - q2.x, dy = py - q2.y, dz = pz - q2.z;
            b2 = fminf(b2, dx * dx + dy * dy + dz * dz);
        }
        {
            float dx = px - q3.x, dy = py - q3.y, dz = pz - q3.z;
            b3 = fminf(b3, dx * dx + dy * dy + dz * dz);
        }
    }
    float best = fminf(fminf(b0, b1), fminf(b2, b3));

    // Wave-level sum of the per-query mins, then one atomicAdd per wave.
    float v = best;
    #pragma unroll
    for (int off = 32; off > 0; off >>= 1) v += __shfl_down(v, off, 64);
    if ((threadIdx.x & 63) == 0) {
        atomicAdd(out, v * (1.0f / ((float)BATCH * (float)NPTS)));
    }
}

extern "C" void kernel_launch(void* const* d_in, const int* in_sizes, int n_in,
                              void* d_out, int out_size, void* d_ws, size_t ws_size,
                              hipStream_t stream) {
    const float* x = (const float*)d_in[0];
    const float* y = (const float*)d_in[1];
    float* out = (float*)d_out;

    hipLaunchKernelGGL(zero_out, dim3(1), dim3(1), 0, stream, out);
    hipLaunchKernelGGL(chamfer_kernel, dim3(2 * BATCH * CHUNKS), dim3(BLOCK), 0,
                       stream, x, y, out);
}

// Round 2
// 167.877 us; speedup vs baseline: 1.1549x; 1.1549x over previous
//
#include <hip/hip_runtime.h>
#include <math.h>

// Chamfer distance, B=16, N=M=4096, fp32 3-D points — single pass over unique
// pairs. Each block: 1024 queries (Q=4/thread, in regs) x 512 targets (LDS).
// Row-mins in registers; col-mins via DPP wave-min (pure VALU) into per-wave
// LDS slices. Partials merged with global atomicMin on uint bit patterns
// (valid: d >= 0, init +inf). Finalize kernel sums all mins.

constexpr int BATCH   = 16;
constexpr int NPTS    = 4096;
constexpr int BLOCK   = 256;              // 4 waves
constexpr int Q       = 4;                // queries per thread
constexpr int TQ      = BLOCK * Q;        // 1024 queries per block
constexpr int QCHUNKS = NPTS / TQ;        // 4
constexpr int T       = 512;              // targets per block
constexpr int TCHUNKS = NPTS / T;         // 8
constexpr int NMIN    = 2 * BATCH * NPTS; // 131072 mins (rows then cols)

__global__ void init_ws(unsigned int* ws, float* out) {
    int i = blockIdx.x * blockDim.x + threadIdx.x;
    if (i < NMIN) ws[i] = 0x7F800000u;    // +inf
    if (i == 0) out[0] = 0.0f;
}

// Full 64-lane min, pure VALU via DPP. Result valid in lane 63.
__device__ __forceinline__ float wave_min_dpp(float v) {
    int t;
    t = __builtin_amdgcn_update_dpp(__float_as_int(v), __float_as_int(v), 0x111, 0xF, 0xF, false); // row_shr:1
    v = fminf(v, __int_as_float(t));
    t = __builtin_amdgcn_update_dpp(__float_as_int(v), __float_as_int(v), 0x112, 0xF, 0xF, false); // row_shr:2
    v = fminf(v, __int_as_float(t));
    t = __builtin_amdgcn_update_dpp(__float_as_int(v), __float_as_int(v), 0x114, 0xF, 0xF, false); // row_shr:4
    v = fminf(v, __int_as_float(t));
    t = __builtin_amdgcn_update_dpp(__float_as_int(v), __float_as_int(v), 0x118, 0xF, 0xF, false); // row_shr:8
    v = fminf(v, __int_as_float(t));
    t = __builtin_amdgcn_update_dpp(__float_as_int(v), __float_as_int(v), 0x142, 0xF, 0xF, false); // row_bcast:15
    v = fminf(v, __int_as_float(t));
    t = __builtin_amdgcn_update_dpp(__float_as_int(v), __float_as_int(v), 0x143, 0xF, 0xF, false); // row_bcast:31
    v = fminf(v, __int_as_float(t));
    return v;
}

__global__ void __launch_bounds__(BLOCK)
chamfer_pairs(const float* __restrict__ x, const float* __restrict__ y,
              unsigned int* __restrict__ rowmin, unsigned int* __restrict__ colmin) {
    __shared__ float4 t_s[T];             // 8 KB: target tile
    __shared__ float  cmin_s[4][T];       // 8 KB: per-wave col-min slices

    const int bid   = blockIdx.x;
    const int batch = bid >> 5;           // 32 blocks per batch
    const int rest  = bid & 31;
    const int qc    = rest >> 3;          // 0..3
    const int tc    = rest & 7;           // 0..7

    const float* Xb = x + (size_t)batch * NPTS * 3;
    const float* Yb = y + (size_t)batch * NPTS * 3;

    // Stage T targets into LDS (each thread: 2 points, 12B contiguous reads).
    for (int i = threadIdx.x; i < T; i += BLOCK) {
        int j = tc * T + i;
        t_s[i] = make_float4(Yb[3 * j], Yb[3 * j + 1], Yb[3 * j + 2], 0.0f);
    }

    // Load Q query points into registers (rows qbase + k*BLOCK + tid).
    float qx[Q], qy[Q], qz[Q], rmin[Q];
    const int qbase = qc * TQ;
    #pragma unroll
    for (int k = 0; k < Q; ++k) {
        int row = qbase + k * BLOCK + threadIdx.x;
        qx[k] = Xb[3 * row];
        qy[k] = Xb[3 * row + 1];
        qz[k] = Xb[3 * row + 2];
        rmin[k] = INFINITY;
    }
    __syncthreads();

    const int  wid  = threadIdx.x >> 6;
    const bool is63 = (threadIdx.x & 63) == 63;

    #pragma unroll 4
    for (int j = 0; j < T; ++j) {
        float4 t4 = t_s[j];               // broadcast read, conflict-free
        float d0, d1, d2, d3;
        {
            float dx = qx[0] - t4.x, dy = qy[0] - t4.y, dz = qz[0] - t4.z;
            d0 = dx * dx + dy * dy + dz * dz;
            rmin[0] = fminf(rmin[0], d0);
        }
        {
            float dx = qx[1] - t4.x, dy = qy[1] - t4.y, dz = qz[1] - t4.z;
            d1 = dx * dx + dy * dy + dz * dz;
            rmin[1] = fminf(rmin[1], d1);
        }
        {
            float dx = qx[2] - t4.x, dy = qy[2] - t4.y, dz = qz[2] - t4.z;
            d2 = dx * dx + dy * dy + dz * dz;
            rmin[2] = fminf(rmin[2], d2);
        }
        {
            float dx = qx[3] - t4.x, dy = qy[3] - t4.y, dz = qz[3] - t4.z;
            d3 = dx * dx + dy * dy + dz * dz;
            rmin[3] = fminf(rmin[3], d3);
        }
        float m  = fminf(fminf(d0, d1), fminf(d2, d3));
        float wm = wave_min_dpp(m);       // lane 63 holds the wave min
        if (is63) cmin_s[wid][j] = wm;
    }
    __syncthreads();

    // Row mins -> global partial merge.
    #pragma unroll
    for (int k = 0; k < Q; ++k) {
        int row = qbase + k * BLOCK + threadIdx.x;
        atomicMin(&rowmin[batch * NPTS + row], __float_as_uint(rmin[k]));
    }
    // Col mins: combine 4 wave slices, then global partial merge.
    for (int i = threadIdx.x; i < T; i += BLOCK) {
        float m = fminf(fminf(cmin_s[0][i], cmin_s[1][i]),
                        fminf(cmin_s[2][i], cmin_s[3][i]));
        atomicMin(&colmin[batch * NPTS + tc * T + i], __float_as_uint(m));
    }
}

__global__ void __launch_bounds__(BLOCK)
finalize(const float* __restrict__ mins, float* __restrict__ out) {
    float s = 0.0f;
    for (int i = blockIdx.x * blockDim.x + threadIdx.x; i < NMIN;
         i += gridDim.x * blockDim.x)
        s += mins[i];
    #pragma unroll
    for (int off = 32; off > 0; off >>= 1) s += __shfl_down(s, off, 64);
    __shared__ float ws_s[4];
    if ((threadIdx.x & 63) == 0) ws_s[threadIdx.x >> 6] = s;
    __syncthreads();
    if (threadIdx.x == 0) {
        float b = ws_s[0] + ws_s[1] + ws_s[2] + ws_s[3];
        atomicAdd(out, b * (1.0f / ((float)BATCH * (float)NPTS)));
    }
}

extern "C" void kernel_launch(void* const* d_in, const int* in_sizes, int n_in,
                              void* d_out, int out_size, void* d_ws, size_t ws_size,
                              hipStream_t stream) {
    const float* x = (const float*)d_in[0];
    const float* y = (const float*)d_in[1];
    float* out = (float*)d_out;
    unsigned int* ws_u = (unsigned int*)d_ws;
    unsigned int* rowmin = ws_u;                 // [16][4096]
    unsigned int* colmin = ws_u + BATCH * NPTS;  // [16][4096]

    hipLaunchKernelGGL(init_ws, dim3((NMIN + BLOCK - 1) / BLOCK), dim3(BLOCK),
                       0, stream, ws_u, out);
    hipLaunchKernelGGL(chamfer_pairs, dim3(BATCH * QCHUNKS * TCHUNKS),
                       dim3(BLOCK), 0, stream, x, y, rowmin, colmin);
    hipLaunchKernelGGL(finalize, dim3(64), dim3(BLOCK), 0, stream,
                       (const float*)ws_u, out);
}

// Round 3
// 141.404 us; speedup vs baseline: 1.3712x; 1.1872x over previous
//
#include <hip/hip_runtime.h>
#include <math.h>

// Chamfer distance, B=16, N=M=4096, fp32 — single pass over unique pairs.
// Block = 512 threads (8 waves), Q=8 queries/thread => 4096 = ALL queries per
// block; T=128 targets staged in LDS. Col-mins complete within a block (plain
// store, no atomics/init). Row-min partials plain-stored per target-chunk and
// reduced in finalize. out[0] zeroed by pairs kernel (kernel-order visible).

constexpr int BATCH   = 16;
constexpr int NPTS    = 4096;
constexpr int BLOCK   = 512;            // 8 waves
constexpr int Q       = 8;              // queries per thread (BLOCK*Q = 4096)
constexpr int T       = 128;            // targets per block
constexpr int TCHUNKS = NPTS / T;       // 32
constexpr int NROW    = BATCH * NPTS;   // 65536
constexpr int NWAVES  = BLOCK / 64;     // 8

// Full 64-lane min, pure VALU via DPP. Result valid in lane 63.
__device__ __forceinline__ float wave_min_dpp(float v) {
    int t;
    t = __builtin_amdgcn_update_dpp(__float_as_int(v), __float_as_int(v), 0x111, 0xF, 0xF, false); // row_shr:1
    v = fminf(v, __int_as_float(t));
    t = __builtin_amdgcn_update_dpp(__float_as_int(v), __float_as_int(v), 0x112, 0xF, 0xF, false); // row_shr:2
    v = fminf(v, __int_as_float(t));
    t = __builtin_amdgcn_update_dpp(__float_as_int(v), __float_as_int(v), 0x114, 0xF, 0xF, false); // row_shr:4
    v = fminf(v, __int_as_float(t));
    t = __builtin_amdgcn_update_dpp(__float_as_int(v), __float_as_int(v), 0x118, 0xF, 0xF, false); // row_shr:8
    v = fminf(v, __int_as_float(t));
    t = __builtin_amdgcn_update_dpp(__float_as_int(v), __float_as_int(v), 0x142, 0xF, 0xF, false); // row_bcast:15
    v = fminf(v, __int_as_float(t));
    t = __builtin_amdgcn_update_dpp(__float_as_int(v), __float_as_int(v), 0x143, 0xF, 0xF, false); // row_bcast:31
    v = fminf(v, __int_as_float(t));
    return v;
}

__global__ void init_rowmin(unsigned int* rowmin) {
    int i = blockIdx.x * blockDim.x + threadIdx.x;
    if (i < NROW) rowmin[i] = 0x7F800000u;  // +inf
}

template <bool DIRECT>
__global__ void __launch_bounds__(BLOCK, 4)
chamfer_pairs(const float* __restrict__ x, const float* __restrict__ y,
              float* __restrict__ colmin, float* __restrict__ rowpart,
              unsigned int* __restrict__ rowmin, float* __restrict__ out) {
    __shared__ float4 t_s[T];               // 2 KB: target tile
    __shared__ float  cmin_s[NWAVES][T];    // 4 KB: per-wave col-min slices

    const int bid   = blockIdx.x;
    const int batch = bid >> 5;             // / TCHUNKS
    const int tc    = bid & (TCHUNKS - 1);

    if (bid == 0 && threadIdx.x == 0) out[0] = 0.0f;  // visible to finalize

    const float* Xb = x + (size_t)batch * NPTS * 3;
    const float* Yb = y + (size_t)batch * NPTS * 3;

    if (threadIdx.x < T) {
        int j = tc * T + threadIdx.x;
        t_s[threadIdx.x] = make_float4(Yb[3 * j], Yb[3 * j + 1], Yb[3 * j + 2], 0.0f);
    }

    float qx[Q], qy[Q], qz[Q], rmin[Q];
    #pragma unroll
    for (int k = 0; k < Q; ++k) {
        int row = k * BLOCK + threadIdx.x;
        qx[k] = Xb[3 * row];
        qy[k] = Xb[3 * row + 1];
        qz[k] = Xb[3 * row + 2];
        rmin[k] = INFINITY;
    }
    __syncthreads();

    const int  wid  = threadIdx.x >> 6;
    const bool is63 = (threadIdx.x & 63) == 63;

    #pragma unroll 4
    for (int j = 0; j < T; ++j) {
        float4 t4 = t_s[j];                 // broadcast read, conflict-free
        float d[Q];
        #pragma unroll
        for (int k = 0; k < Q; ++k) {
            float dx = qx[k] - t4.x, dy = qy[k] - t4.y, dz = qz[k] - t4.z;
            d[k] = dx * dx + dy * dy + dz * dz;
            rmin[k] = fminf(rmin[k], d[k]);
        }
        float m = fminf(fminf(fminf(d[0], d[1]), fminf(d[2], d[3])),
                        fminf(fminf(d[4], d[5]), fminf(d[6], d[7])));
        float wm = wave_min_dpp(m);         // lane 63 holds the wave min
        if (is63) cmin_s[wid][j] = wm;
    }
    __syncthreads();

    // Col-mins are complete (all 4096 queries in this block): plain store.
    if (threadIdx.x < T) {
        float m = cmin_s[0][threadIdx.x];
        #pragma unroll
        for (int w = 1; w < NWAVES; ++w) m = fminf(m, cmin_s[w][threadIdx.x]);
        colmin[batch * NPTS + tc * T + threadIdx.x] = m;
    }

    // Row-min partials (this block covered only T of 4096 targets).
    if (DIRECT) {
        float* rp = rowpart + (size_t)(batch * TCHUNKS + tc) * NPTS;
        #pragma unroll
        for (int k = 0; k < Q; ++k) rp[k * BLOCK + threadIdx.x] = rmin[k];
    } else {
        unsigned int* rm = rowmin + batch * NPTS;
        #pragma unroll
        for (int k = 0; k < Q; ++k)
            atomicMin(&rm[k * BLOCK + threadIdx.x], __float_as_uint(rmin[k]));
    }
}

template <bool DIRECT>
__global__ void __launch_bounds__(256)
finalize(const float* __restrict__ colmin, const float* __restrict__ rowpart,
         const unsigned int* __restrict__ rowmin, float* __restrict__ out) {
    float s = 0.0f;
    for (int r = blockIdx.x * 256 + threadIdx.x; r < NROW;
         r += gridDim.x * 256) {
        float m;
        if (DIRECT) {
            int b = r >> 12, row = r & (NPTS - 1);
            const float* rp = rowpart + (size_t)b * TCHUNKS * NPTS + row;
            m = rp[0];
            #pragma unroll 4
            for (int tc = 1; tc < TCHUNKS; ++tc) m = fminf(m, rp[(size_t)tc * NPTS]);
        } else {
            m = __uint_as_float(rowmin[r]);
        }
        s += m + colmin[r];
    }
    #pragma unroll
    for (int off = 32; off > 0; off >>= 1) s += __shfl_down(s, off, 64);
    __shared__ float ws_s[4];
    if ((threadIdx.x & 63) == 0) ws_s[threadIdx.x >> 6] = s;
    __syncthreads();
    if (threadIdx.x == 0) {
        float b = ws_s[0] + ws_s[1] + ws_s[2] + ws_s[3];
        atomicAdd(out, b * (1.0f / ((float)BATCH * (float)NPTS)));
    }
}

extern "C" void kernel_launch(void* const* d_in, const int* in_sizes, int n_in,
                              void* d_out, int out_size, void* d_ws, size_t ws_size,
                              hipStream_t stream) {
    const float* x = (const float*)d_in[0];
    const float* y = (const float*)d_in[1];
    float* out = (float*)d_out;

    float* colmin = (float*)d_ws;                         // [16][4096]  256 KB
    const size_t direct_bytes =
        (size_t)NROW * 4 + (size_t)NROW * TCHUNKS * 4;    // colmin + rowpart

    if (ws_size >= direct_bytes) {
        float* rowpart = colmin + NROW;                   // [16*32][4096] 8 MB
        hipLaunchKernelGGL((chamfer_pairs<true>), dim3(BATCH * TCHUNKS),
                           dim3(BLOCK), 0, stream, x, y, colmin, rowpart,
                           (unsigned int*)nullptr, out);
        hipLaunchKernelGGL((finalize<true>), dim3(128), dim3(256), 0, stream,
                           colmin, rowpart, (const unsigned int*)nullptr, out);
    } else {
        unsigned int* rowmin = (unsigned int*)(colmin + NROW);  // 256 KB
        hipLaunchKernelGGL(init_rowmin, dim3((NROW + 255) / 256), dim3(256),
                           0, stream, rowmin);
        hipLaunchKernelGGL((chamfer_pairs<false>), dim3(BATCH * TCHUNKS),
                           dim3(BLOCK), 0, stream, x, y, colmin,
                           (float*)nullptr, rowmin, out);
        hipLaunchKernelGGL((finalize<false>), dim3(128), dim3(256), 0, stream,
                           colmin, (const float*)nullptr, rowmin, out);
    }
}

// Round 4
// 137.997 us; speedup vs baseline: 1.4050x; 1.0247x over previous
//
#include <hip/hip_runtime.h>
#include <math.h>

// Chamfer distance, B=16, N=M=4096, fp32 — single pass over unique pairs.
// Block = 1024 threads (16 waves), Q=4 queries/thread => 4096 = ALL queries
// per block (col-mins block-complete, plain store). T=128 targets in LDS,
// stored NEGATED and DUPLICATED per component ({-t,-t}) so the distance
// computation maps to packed fp32 (v_pk_add/v_pk_mul/v_pk_fma_f32, gfx90a+
// FeaturePackedFP32Ops): each thread packs 2 queries per pk op.
// Row-min partials plain-stored per target-chunk, reduced in finalize.

typedef float v2f __attribute__((ext_vector_type(2)));

constexpr int BATCH   = 16;
constexpr int NPTS    = 4096;
constexpr int BLOCK   = 1024;           // 16 waves
constexpr int Q       = 4;              // queries per thread (BLOCK*Q = 4096)
constexpr int T       = 128;            // targets per block
constexpr int TCHUNKS = NPTS / T;       // 32
constexpr int NROW    = BATCH * NPTS;   // 65536
constexpr int NWAVES  = BLOCK / 64;     // 16

// Full 64-lane min, pure VALU via DPP. Result valid in lane 63.
__device__ __forceinline__ float wave_min_dpp(float v) {
    int t;
    t = __builtin_amdgcn_update_dpp(__float_as_int(v), __float_as_int(v), 0x111, 0xF, 0xF, false); // row_shr:1
    v = fminf(v, __int_as_float(t));
    t = __builtin_amdgcn_update_dpp(__float_as_int(v), __float_as_int(v), 0x112, 0xF, 0xF, false); // row_shr:2
    v = fminf(v, __int_as_float(t));
    t = __builtin_amdgcn_update_dpp(__float_as_int(v), __float_as_int(v), 0x114, 0xF, 0xF, false); // row_shr:4
    v = fminf(v, __int_as_float(t));
    t = __builtin_amdgcn_update_dpp(__float_as_int(v), __float_as_int(v), 0x118, 0xF, 0xF, false); // row_shr:8
    v = fminf(v, __int_as_float(t));
    t = __builtin_amdgcn_update_dpp(__float_as_int(v), __float_as_int(v), 0x142, 0xF, 0xF, false); // row_bcast:15
    v = fminf(v, __int_as_float(t));
    t = __builtin_amdgcn_update_dpp(__float_as_int(v), __float_as_int(v), 0x143, 0xF, 0xF, false); // row_bcast:31
    v = fminf(v, __int_as_float(t));
    return v;
}

__global__ void init_rowmin(unsigned int* rowmin) {
    int i = blockIdx.x * blockDim.x + threadIdx.x;
    if (i < NROW) rowmin[i] = 0x7F800000u;  // +inf
}

template <bool DIRECT>
__global__ void __launch_bounds__(BLOCK, 8)
chamfer_pairs(const float* __restrict__ x, const float* __restrict__ y,
              float* __restrict__ colmin, float* __restrict__ rowpart,
              unsigned int* __restrict__ rowmin, float* __restrict__ out) {
    __shared__ v2f   t_s[T][4];             // 4 KB: {-t,-t} per comp, 32B pad
    __shared__ float cmin_s[NWAVES][T];     // 8 KB: per-wave col-min slices

    const int bid   = blockIdx.x;
    const int batch = bid >> 5;             // / TCHUNKS
    const int tc    = bid & (TCHUNKS - 1);

    if (bid == 0 && threadIdx.x == 0) out[0] = 0.0f;  // visible to finalize

    const float* Xb = x + (size_t)batch * NPTS * 3;
    const float* Yb = y + (size_t)batch * NPTS * 3;

    if (threadIdx.x < T) {
        int j = tc * T + threadIdx.x;
        float a = Yb[3 * j], b = Yb[3 * j + 1], c = Yb[3 * j + 2];
        t_s[threadIdx.x][0] = (v2f){-a, -a};
        t_s[threadIdx.x][1] = (v2f){-b, -b};
        t_s[threadIdx.x][2] = (v2f){-c, -c};
    }

    // Load Q=4 query points; pack queries (kp, kp+2) into v2f pairs.
    float qx[Q], qy[Q], qz[Q];
    #pragma unroll
    for (int k = 0; k < Q; ++k) {
        int row = k * BLOCK + threadIdx.x;
        qx[k] = Xb[3 * row];
        qy[k] = Xb[3 * row + 1];
        qz[k] = Xb[3 * row + 2];
    }
    v2f qx2[2], qy2[2], qz2[2];
    #pragma unroll
    for (int kp = 0; kp < 2; ++kp) {
        qx2[kp] = (v2f){qx[kp], qx[kp + 2]};
        qy2[kp] = (v2f){qy[kp], qy[kp + 2]};
        qz2[kp] = (v2f){qz[kp], qz[kp + 2]};
    }
    float rmin[Q];
    #pragma unroll
    for (int k = 0; k < Q; ++k) rmin[k] = INFINITY;

    __syncthreads();

    const int  wid  = threadIdx.x >> 6;
    const bool is63 = (threadIdx.x & 63) == 63;

    #pragma unroll 4
    for (int j = 0; j < T; ++j) {
        v2f ntx = t_s[j][0], nty = t_s[j][1], ntz = t_s[j][2];
        v2f d2[2];
        #pragma unroll
        for (int kp = 0; kp < 2; ++kp) {
            v2f dx = qx2[kp] + ntx;         // v_pk_add_f32
            v2f dy = qy2[kp] + nty;
            v2f dz = qz2[kp] + ntz;
            d2[kp] = dx * dx + dy * dy + dz * dz;  // pk_mul + 2x pk_fma
        }
        rmin[0] = fminf(rmin[0], d2[0].x);
        rmin[2] = fminf(rmin[2], d2[0].y);
        rmin[1] = fminf(rmin[1], d2[1].x);
        rmin[3] = fminf(rmin[3], d2[1].y);
        float m = fminf(fminf(d2[0].x, d2[0].y), fminf(d2[1].x, d2[1].y));
        float wm = wave_min_dpp(m);         // lane 63 holds the wave min
        if (is63) cmin_s[wid][j] = wm;
    }
    __syncthreads();

    // Col-mins complete (all 4096 queries in this block): plain store.
    if (threadIdx.x < T) {
        float m = cmin_s[0][threadIdx.x];
        #pragma unroll
        for (int w = 1; w < NWAVES; ++w) m = fminf(m, cmin_s[w][threadIdx.x]);
        colmin[batch * NPTS + tc * T + threadIdx.x] = m;
    }

    // Row-min partials (this block covered only T of 4096 targets).
    if (DIRECT) {
        float* rp = rowpart + (size_t)(batch * TCHUNKS + tc) * NPTS;
        #pragma unroll
        for (int k = 0; k < Q; ++k) rp[k * BLOCK + threadIdx.x] = rmin[k];
    } else {
        unsigned int* rm = rowmin + batch * NPTS;
        #pragma unroll
        for (int k = 0; k < Q; ++k)
            atomicMin(&rm[k * BLOCK + threadIdx.x], __float_as_uint(rmin[k]));
    }
}

template <bool DIRECT>
__global__ void __launch_bounds__(256)
finalize(const float* __restrict__ colmin, const float* __restrict__ rowpart,
         const unsigned int* __restrict__ rowmin, float* __restrict__ out) {
    float s = 0.0f;
    for (int r = blockIdx.x * 256 + threadIdx.x; r < NROW;
         r += gridDim.x * 256) {
        float m;
        if (DIRECT) {
            int b = r >> 12, row = r & (NPTS - 1);
            const float* rp = rowpart + (size_t)b * TCHUNKS * NPTS + row;
            m = rp[0];
            #pragma unroll 4
            for (int tc = 1; tc < TCHUNKS; ++tc) m = fminf(m, rp[(size_t)tc * NPTS]);
        } else {
            m = __uint_as_float(rowmin[r]);
        }
        s += m + colmin[r];
    }
    #pragma unroll
    for (int off = 32; off > 0; off >>= 1) s += __shfl_down(s, off, 64);
    __shared__ float ws_s[4];
    if ((threadIdx.x & 63) == 0) ws_s[threadIdx.x >> 6] = s;
    __syncthreads();
    if (threadIdx.x == 0) {
        float b = ws_s[0] + ws_s[1] + ws_s[2] + ws_s[3];
        atomicAdd(out, b * (1.0f / ((float)BATCH * (float)NPTS)));
    }
}

extern "C" void kernel_launch(void* const* d_in, const int* in_sizes, int n_in,
                              void* d_out, int out_size, void* d_ws, size_t ws_size,
                              hipStream_t stream) {
    const float* x = (const float*)d_in[0];
    const float* y = (const float*)d_in[1];
    float* out = (float*)d_out;

    float* colmin = (float*)d_ws;                         // [16][4096]  256 KB
    const size_t direct_bytes =
        (size_t)NROW * 4 + (size_t)NROW * TCHUNKS * 4;    // colmin + rowpart

    if (ws_size >= direct_bytes) {
        float* rowpart = colmin + NROW;                   // [16*32][4096] 8 MB
        hipLaunchKernelGGL((chamfer_pairs<true>), dim3(BATCH * TCHUNKS),
                           dim3(BLOCK), 0, stream, x, y, colmin, rowpart,
                           (unsigned int*)nullptr, out);
        hipLaunchKernelGGL((finalize<true>), dim3(256), dim3(256), 0, stream,
                           colmin, rowpart, (const unsigned int*)nullptr, out);
    } else {
        unsigned int* rowmin = (unsigned int*)(colmin + NROW);  // 256 KB
        hipLaunchKernelGGL(init_rowmin, dim3((NROW + 255) / 256), dim3(256),
                           0, stream, rowmin);
        hipLaunchKernelGGL((chamfer_pairs<false>), dim3(BATCH * TCHUNKS),
                           dim3(BLOCK), 0, stream, x, y, colmin,
                           (float*)nullptr, rowmin, out);
        hipLaunchKernelGGL((finalize<false>), dim3(256), dim3(256), 0, stream,
                           colmin, (const float*)nullptr, rowmin, out);
    }
}

// Round 5
// 124.105 us; speedup vs baseline: 1.5623x; 1.1119x over previous
//
#include <hip/hip_runtime.h>
#include <math.h>

// Chamfer distance, B=16, N=M=4096, fp32 — row-mins only, both directions as
// separate grid slices (redundant distance compute is cheaper than any
// cross-lane col-min reduction). Block = 512 thr (8 waves), Q=8 queries/thread
// => 4096 = ALL queries per (dir,batch); T=128 targets in LDS, stored NEGATED
// + DUPLICATED ({-t,-t}) so distances are pure packed fp32 (v_pk_add/fma).
// Inner loop per j per wave: 24 pk + 8 min — no reductions, no divergence.
// Row partials per target-chunk plain-stored; float4 finalize reduces.

typedef float v2f __attribute__((ext_vector_type(2)));

constexpr int BATCH = 16;
constexpr int NPTS  = 4096;
constexpr int BLOCK = 512;              // 8 waves
constexpr int Q     = 8;                // queries/thread; BLOCK*Q = 4096 = all
constexpr int TC    = 32;               // target chunks per (dir,batch)
constexpr int T     = NPTS / TC;        // 128 targets per block
constexpr int NROW  = 2 * BATCH * NPTS; // 131072 final row-mins

__global__ void init_rowmin(unsigned int* rowmin) {
    int i = blockIdx.x * blockDim.x + threadIdx.x;
    if (i < NROW) rowmin[i] = 0x7F800000u;  // +inf
}

template <bool DIRECT>
__global__ void __launch_bounds__(BLOCK, 8)
chamfer_rows(const float* __restrict__ x, const float* __restrict__ y,
             float* __restrict__ rowpart, unsigned int* __restrict__ rowmin,
             float* __restrict__ out) {
    __shared__ v2f t_s[T][4];           // 4 KB: {-t,-t} x,y,z + pad (b128 align)

    const int bid   = blockIdx.x;
    const int dir   = bid >> 9;         // 512 blocks per direction
    const int batch = (bid >> 5) & (BATCH - 1);
    const int tc    = bid & (TC - 1);

    if (bid == 0 && threadIdx.x == 0) out[0] = 0.0f;  // visible to finalize

    const float* P  = dir ? y : x;      // queries
    const float* G  = dir ? x : y;      // targets
    const float* Pb = P + (size_t)batch * NPTS * 3;
    const float* Gb = G + (size_t)batch * NPTS * 3;

    if (threadIdx.x < T) {
        int j = tc * T + threadIdx.x;
        float a = Gb[3 * j], b = Gb[3 * j + 1], c = Gb[3 * j + 2];
        t_s[threadIdx.x][0] = (v2f){-a, -a};
        t_s[threadIdx.x][1] = (v2f){-b, -b};
        t_s[threadIdx.x][2] = (v2f){-c, -c};
    }

    // Q=8 queries; pack (k, k+4) into v2f lanes for packed-fp32 math.
    float qx[Q], qy[Q], qz[Q];
    #pragma unroll
    for (int k = 0; k < Q; ++k) {
        int row = k * BLOCK + threadIdx.x;
        qx[k] = Pb[3 * row];
        qy[k] = Pb[3 * row + 1];
        qz[k] = Pb[3 * row + 2];
    }
    v2f qx2[4], qy2[4], qz2[4];
    #pragma unroll
    for (int kp = 0; kp < 4; ++kp) {
        qx2[kp] = (v2f){qx[kp], qx[kp + 4]};
        qy2[kp] = (v2f){qy[kp], qy[kp + 4]};
        qz2[kp] = (v2f){qz[kp], qz[kp + 4]};
    }
    float rmin[Q];
    #pragma unroll
    for (int k = 0; k < Q; ++k) rmin[k] = INFINITY;

    __syncthreads();

    #pragma unroll 4
    for (int j = 0; j < T; ++j) {
        v2f ntx = t_s[j][0], nty = t_s[j][1], ntz = t_s[j][2];  // broadcast
        #pragma unroll
        for (int kp = 0; kp < 4; ++kp) {
            v2f dx = qx2[kp] + ntx;       // v_pk_add_f32
            v2f dy = qy2[kp] + nty;
            v2f dz = qz2[kp] + ntz;
            v2f d  = dx * dx + dy * dy + dz * dz;  // pk mul/fma
            rmin[kp]     = fminf(rmin[kp],     d.x);
            rmin[kp + 4] = fminf(rmin[kp + 4], d.y);
        }
    }

    if (DIRECT) {
        float* rp = rowpart + ((size_t)((dir * BATCH + batch) * TC + tc)) * NPTS;
        #pragma unroll
        for (int k = 0; k < Q; ++k) rp[k * BLOCK + threadIdx.x] = rmin[k];
    } else {
        unsigned int* rm = rowmin + (dir * BATCH + batch) * NPTS;
        #pragma unroll
        for (int k = 0; k < Q; ++k)
            atomicMin(&rm[k * BLOCK + threadIdx.x], __float_as_uint(rmin[k]));
    }
}

template <bool DIRECT>
__global__ void __launch_bounds__(256)
finalize(const float* __restrict__ rowpart,
         const unsigned int* __restrict__ rowmin, float* __restrict__ out) {
    float s = 0.0f;
    if (DIRECT) {
        const int n4 = NROW / 4;
        for (int i = blockIdx.x * 256 + threadIdx.x; i < n4;
             i += gridDim.x * 256) {
            int g   = i * 4;
            int db  = g >> 12;              // (dir*BATCH+batch)
            int row = g & (NPTS - 1);
            const float* rp = rowpart + ((size_t)db * TC) * NPTS + row;
            float4 m = *(const float4*)rp;
            #pragma unroll 4
            for (int tc = 1; tc < TC; ++tc) {
                float4 v = *(const float4*)(rp + (size_t)tc * NPTS);
                m.x = fminf(m.x, v.x); m.y = fminf(m.y, v.y);
                m.z = fminf(m.z, v.z); m.w = fminf(m.w, v.w);
            }
            s += (m.x + m.y) + (m.z + m.w);
        }
    } else {
        for (int i = blockIdx.x * 256 + threadIdx.x; i < NROW;
             i += gridDim.x * 256)
            s += __uint_as_float(rowmin[i]);
    }
    #pragma unroll
    for (int off = 32; off > 0; off >>= 1) s += __shfl_down(s, off, 64);
    __shared__ float ws_s[4];
    if ((threadIdx.x & 63) == 0) ws_s[threadIdx.x >> 6] = s;
    __syncthreads();
    if (threadIdx.x == 0) {
        float b = ws_s[0] + ws_s[1] + ws_s[2] + ws_s[3];
        atomicAdd(out, b * (1.0f / ((float)BATCH * (float)NPTS)));
    }
}

extern "C" void kernel_launch(void* const* d_in, const int* in_sizes, int n_in,
                              void* d_out, int out_size, void* d_ws, size_t ws_size,
                              hipStream_t stream) {
    const float* x = (const float*)d_in[0];
    const float* y = (const float*)d_in[1];
    float* out = (float*)d_out;

    const size_t direct_bytes = (size_t)NROW * TC * 4;   // 16.8 MB

    if (ws_size >= direct_bytes) {
        float* rowpart = (float*)d_ws;   // [2*16*32][4096]
        hipLaunchKernelGGL((chamfer_rows<true>), dim3(2 * BATCH * TC),
                           dim3(BLOCK), 0, stream, x, y, rowpart,
                           (unsigned int*)nullptr, out);
        hipLaunchKernelGGL((finalize<true>), dim3(128), dim3(256), 0, stream,
                           rowpart, (const unsigned int*)nullptr, out);
    } else {
        unsigned int* rowmin = (unsigned int*)d_ws;       // 512 KB
        hipLaunchKernelGGL(init_rowmin, dim3((NROW + 255) / 256), dim3(256),
                           0, stream, rowmin);
        hipLaunchKernelGGL((chamfer_rows<false>), dim3(2 * BATCH * TC),
                           dim3(BLOCK), 0, stream, x, y, (float*)nullptr,
                           rowmin, out);
        hipLaunchKernelGGL((finalize<false>), dim3(128), dim3(256), 0, stream,
                           (const float*)nullptr, rowmin, out);
    }
}

// Round 6
// 105.825 us; speedup vs baseline: 1.8322x; 1.1727x over previous
//
#include <hip/hip_runtime.h>
#include <math.h>

// Chamfer distance, B=16, N=M=4096, fp32 — row-mins both directions.
// R6: force packed fp32 via inline-asm v_pk_fma_f32 (R5 showed the compiler
// scalarized <2 x float>), norm-expansion d' = -2q.t + t^2 (q^2 added once at
// the end), and TARGET-PAIR packing: each pk op computes d' for one query vs
// two consecutive targets. Queries are duplicated {q,q} in registers (once);
// LDS stores {-2tx_j,-2tx_j1}{-2ty..}{-2tz..}{t2_j,t2_j1} = 16 B/target,
// read as 2x ds_read_b128 per target-pair. Row min via v_min3_f32 fold.

typedef float v2f __attribute__((ext_vector_type(2)));

constexpr int BATCH = 16;
constexpr int NPTS  = 4096;
constexpr int BLOCK = 512;              // 8 waves; BLOCK*Q = 4096 = all rows
constexpr int Q     = 8;                // queries per thread
constexpr int TC    = 32;               // target chunks per (dir,batch)
constexpr int T     = NPTS / TC;        // 128 targets per block
constexpr int TP    = T / 2;            // 64 target-pair slots
constexpr int NROW  = 2 * BATCH * NPTS; // 131072 final row-mins

__global__ void init_rowmin(unsigned int* rowmin) {
    int i = blockIdx.x * blockDim.x + threadIdx.x;
    if (i < NROW) rowmin[i] = 0x7F800000u;  // +inf
}

template <bool DIRECT>
__global__ void __launch_bounds__(BLOCK, 4)
chamfer_rows(const float* __restrict__ x, const float* __restrict__ y,
             float* __restrict__ rowpart, unsigned int* __restrict__ rowmin,
             float* __restrict__ out) {
    __shared__ v2f t_s[TP][4];          // 2 KB: per pair-slot {tx2,ty2,tz2,ss}

    const int bid   = blockIdx.x;
    const int dir   = bid >> 9;         // 512 blocks per direction
    const int batch = (bid >> 5) & (BATCH - 1);
    const int tc    = bid & (TC - 1);

    if (bid == 0 && threadIdx.x == 0) out[0] = 0.0f;  // visible to finalize

    const float* P  = dir ? y : x;      // queries
    const float* G  = dir ? x : y;      // targets
    const float* Pb = P + (size_t)batch * NPTS * 3;
    const float* Gb = G + (size_t)batch * NPTS * 3;

    // Stage T targets: thread i < T handles target j=i, half h=i&1 of slot i>>1.
    if (threadIdx.x < T) {
        int j = tc * T + threadIdx.x;
        int slot = threadIdx.x >> 1, h = threadIdx.x & 1;
        float a = Gb[3 * j], b = Gb[3 * j + 1], c = Gb[3 * j + 2];
        float* base = (float*)&t_s[slot][0];
        base[0 * 2 + h] = -2.0f * a;
        base[1 * 2 + h] = -2.0f * b;
        base[2 * 2 + h] = -2.0f * c;
        base[3 * 2 + h] = a * a + b * b + c * c;
    }

    // Q queries per thread, duplicated {q,q} once; q^2 kept for the epilogue.
    v2f QX[Q], QY[Q], QZ[Q];
    float qsq[Q], rmin[Q];
    #pragma unroll
    for (int k = 0; k < Q; ++k) {
        int row = k * BLOCK + threadIdx.x;
        float a = Pb[3 * row], b = Pb[3 * row + 1], c = Pb[3 * row + 2];
        QX[k] = (v2f){a, a};
        QY[k] = (v2f){b, b};
        QZ[k] = (v2f){c, c};
        qsq[k] = a * a + b * b + c * c;
        rmin[k] = INFINITY;
    }
    __syncthreads();

    #pragma unroll 4
    for (int J = 0; J < TP; ++J) {
        v2f TX = t_s[J][0], TY = t_s[J][1], TZ = t_s[J][2], SS = t_s[J][3];
        #pragma unroll
        for (int k = 0; k < Q; ++k) {
            v2f d;
            // d = qx*(-2tx) + t2 ; d += qy*(-2ty) ; d += qz*(-2tz)
            asm("v_pk_fma_f32 %0, %1, %2, %3"
                : "=v"(d) : "v"(QX[k]), "v"(TX), "v"(SS));
            asm("v_pk_fma_f32 %0, %1, %2, %0"
                : "+v"(d) : "v"(QY[k]), "v"(TY));
            asm("v_pk_fma_f32 %0, %1, %2, %0"
                : "+v"(d) : "v"(QZ[k]), "v"(TZ));
            rmin[k] = fminf(fminf(rmin[k], d.x), d.y);   // -> v_min3_f32
        }
    }

    if (DIRECT) {
        float* rp = rowpart + ((size_t)((dir * BATCH + batch) * TC + tc)) * NPTS;
        #pragma unroll
        for (int k = 0; k < Q; ++k)
            rp[k * BLOCK + threadIdx.x] = rmin[k] + qsq[k];
    } else {
        // uint-bit atomicMin needs non-negative floats; clamp the ~1e-6
        // negative cancellation residue (error << threshold).
        unsigned int* rm = rowmin + (dir * BATCH + batch) * NPTS;
        #pragma unroll
        for (int k = 0; k < Q; ++k)
            atomicMin(&rm[k * BLOCK + threadIdx.x],
                      __float_as_uint(fmaxf(rmin[k] + qsq[k], 0.0f)));
    }
}

template <bool DIRECT>
__global__ void __launch_bounds__(256)
finalize(const float* __restrict__ rowpart,
         const unsigned int* __restrict__ rowmin, float* __restrict__ out) {
    float s = 0.0f;
    if (DIRECT) {
        const int n4 = NROW / 4;
        for (int i = blockIdx.x * 256 + threadIdx.x; i < n4;
             i += gridDim.x * 256) {
            int g   = i * 4;
            int db  = g >> 12;              // (dir*BATCH+batch)
            int row = g & (NPTS - 1);
            const float* rp = rowpart + ((size_t)db * TC) * NPTS + row;
            float4 m = *(const float4*)rp;
            #pragma unroll 4
            for (int tc = 1; tc < TC; ++tc) {
                float4 v = *(const float4*)(rp + (size_t)tc * NPTS);
                m.x = fminf(m.x, v.x); m.y = fminf(m.y, v.y);
                m.z = fminf(m.z, v.z); m.w = fminf(m.w, v.w);
            }
            s += (m.x + m.y) + (m.z + m.w);
        }
    } else {
        for (int i = blockIdx.x * 256 + threadIdx.x; i < NROW;
             i += gridDim.x * 256)
            s += __uint_as_float(rowmin[i]);
    }
    #pragma unroll
    for (int off = 32; off > 0; off >>= 1) s += __shfl_down(s, off, 64);
    __shared__ float ws_s[4];
    if ((threadIdx.x & 63) == 0) ws_s[threadIdx.x >> 6] = s;
    __syncthreads();
    if (threadIdx.x == 0) {
        float b = ws_s[0] + ws_s[1] + ws_s[2] + ws_s[3];
        atomicAdd(out, b * (1.0f / ((float)BATCH * (float)NPTS)));
    }
}

extern "C" void kernel_launch(void* const* d_in, const int* in_sizes, int n_in,
                              void* d_out, int out_size, void* d_ws, size_t ws_size,
                              hipStream_t stream) {
    const float* x = (const float*)d_in[0];
    const float* y = (const float*)d_in[1];
    float* out = (float*)d_out;

    const size_t direct_bytes = (size_t)NROW * TC * 4;   // 16.8 MB

    if (ws_size >= direct_bytes) {
        float* rowpart = (float*)d_ws;   // [2*16*32][4096]
        hipLaunchKernelGGL((chamfer_rows<true>), dim3(2 * BATCH * TC),
                           dim3(BLOCK), 0, stream, x, y, rowpart,
                           (unsigned int*)nullptr, out);
        hipLaunchKernelGGL((finalize<true>), dim3(128), dim3(256), 0, stream,
                           rowpart, (const unsigned int*)nullptr, out);
    } else {
        unsigned int* rowmin = (unsigned int*)d_ws;       // 512 KB
        hipLaunchKernelGGL(init_rowmin, dim3((NROW + 255) / 256), dim3(256),
                           0, stream, rowmin);
        hipLaunchKernelGGL((chamfer_rows<false>), dim3(2 * BATCH * TC),
                           dim3(BLOCK), 0, stream, x, y, (float*)nullptr,
                           rowmin, out);
        hipLaunchKernelGGL((finalize<false>), dim3(128), dim3(256), 0, stream,
                           (const float*)nullptr, rowmin, out);
    }
}